// Round 10
// baseline (70.201 us; speedup 1.0000x reference)
//
#include <hip/hip_runtime.h>

#define BB 64
#define TT 8192
#define CC 64

typedef float vfloat4 __attribute__((ext_vector_type(4)));

// DPP cross-lane helpers (VALU-only, no LDS). CTRL: 0x141 = row_half_mirror
// (lane^7 within each 8-group), 0x4E = quad_perm [2,3,0,1] (lane^2),
// 0xB1 = quad_perm [1,0,3,2] (lane^1). All stay within an 8-lane group.
template<int CTRL>
__device__ __forceinline__ float dppf(float x) {
    return __int_as_float(__builtin_amdgcn_update_dpp(
        0, __float_as_int(x), CTRL, 0xF, 0xF, true));
}
template<int CTRL>
__device__ __forceinline__ int dppi(int x) {
    return __builtin_amdgcn_update_dpp(0, x, CTRL, 0xF, 0xF, true);
}

// ---------------- K1: masked argmax over C=64 -> preds[B*T] ----------------
// 8 lanes per frame, 8 cols/lane (2x float4), DPP-only reduction.
// Masked frames skip the 256B logits read entirely (wave-coherent tails).
__global__ __launch_bounds__(256) void k_argmax(const float* __restrict__ logits,
                                                const int* __restrict__ mask,
                                                int* __restrict__ preds) {
    const int lane = threadIdx.x & 63;
    const int wave = threadIdx.x >> 6;
    const int sub  = lane & 7;    // column octet within frame
    const int fidx = lane >> 3;   // frame within group of 8
    const int wavesPerBlock = blockDim.x >> 6;
    const int gw = blockIdx.x * wavesPerBlock + wave;
    const int nw = gridDim.x * wavesPerBlock;
    const int ngroups = (BB * TT) >> 3;   // 8 frames per wave-iteration

    #pragma unroll 2
    for (int g = gw; g < ngroups; g += nw) {
        const int f = g * 8 + fidx;
        const int mk = mask[f];
        int li = -1;
        if (!mk) {
            const float* row = logits + (size_t)f * CC + sub * 8;
            const float4 v0 = *reinterpret_cast<const float4*>(row);
            const float4 v1 = *reinterpret_cast<const float4*>(row + 4);
            // local max over 8 cols
            float m = fmaxf(fmaxf(fmaxf(v0.x, v0.y), fmaxf(v0.z, v0.w)),
                            fmaxf(fmaxf(v1.x, v1.y), fmaxf(v1.z, v1.w)));
            // 8-lane max reduce via DPP (pure VALU; all 8 lanes of a frame
            // share the mask, so active groups are fully active)
            m = fmaxf(m, dppf<0x141>(m));   // ^7
            m = fmaxf(m, dppf<0x4E>(m));    // ^2
            m = fmaxf(m, dppf<0xB1>(m));    // ^1
            // local first index equal to global max
            const int c0 = sub * 8;
            int t = 64;
            if (v1.w == m) t = c0 + 7;
            if (v1.z == m) t = c0 + 6;
            if (v1.y == m) t = c0 + 5;
            if (v1.x == m) t = c0 + 4;
            if (v0.w == m) t = c0 + 3;
            if (v0.z == m) t = c0 + 2;
            if (v0.y == m) t = c0 + 1;
            if (v0.x == m) t = c0 + 0;
            // 8-lane min-index reduce
            t = min(t, dppi<0x141>(t));
            t = min(t, dppi<0x4E>(t));
            t = min(t, dppi<0xB1>(t));
            li = t;
        }
        if (sub == 0) preds[f] = li;
    }
}

// ---------------- block-wide exclusive scan (1024 thr = 16 waves) ----------------
// Wave-level shfl_up scan + 16-entry wave-sum combine. ~3 barriers total.
__device__ __forceinline__ void block_scan(int x, int tid, int* s_wsum,
                                           int& excl, int& total) {
    const int lane = tid & 63;
    const int wv   = tid >> 6;
    int v = x;
    #pragma unroll
    for (int d = 1; d < 64; d <<= 1) {
        int t = __shfl_up(v, d);
        if (lane >= d) v += t;
    }
    __syncthreads();                 // s_wsum safe to overwrite
    if (lane == 63) s_wsum[wv] = v;
    __syncthreads();
    int wpre = 0, tot = 0;
    #pragma unroll
    for (int w = 0; w < 16; ++w) {
        const int s = s_wsum[w];
        tot += s;
        if (w < wv) wpre += s;
    }
    excl = wpre + v - x;
    total = tot;
}

// ---------------- K2: per-batch RLE + compaction scans + pad write ----------------
// One block (1024 threads) per batch. Emits packed (start | count<<14).
__global__ __launch_bounds__(1024) void k_rle(const int* __restrict__ preds,
                                              unsigned int* __restrict__ g_sc,
                                              int* __restrict__ g_newsz,
                                              float* __restrict__ out_pad) {
    __shared__ int s_pred[TT];
    __shared__ int s_start[TT];
    __shared__ int s_wsum[16];
    const int b   = blockIdx.x;
    const int tid = threadIdx.x;
    const int NT  = 1024;
    const int CHUNK = TT / NT;     // 8
    const int t0 = tid * CHUNK;

    // load preds row (int4 vectorized)
    {
        const int4* src = reinterpret_cast<const int4*>(preds + (size_t)b * TT);
        int4* dst = reinterpret_cast<int4*>(s_pred);
        for (int i = tid; i < TT / 4; i += NT) dst[i] = src[i];
    }
    __syncthreads();

    // ---- scan 1: boundaries -> segment starts ----
    int local = 0;
    for (int t = t0; t < t0 + CHUNK; ++t) {
        local += (t == 0) || (s_pred[t] != s_pred[t - 1]);
    }
    int run, num_segs;
    block_scan(local, tid, s_wsum, run, num_segs);
    for (int t = t0; t < t0 + CHUNK; ++t) {
        int bnd = (t == 0) || (s_pred[t] != s_pred[t - 1]);
        if (bnd) { run++; s_start[run - 1] = t; }
    }
    __syncthreads();

    // ---- scan 2: keep -> compacted positions; emit packed (start,count) ----
    int lk = 0;
    for (int s = t0; s < t0 + CHUNK; ++s) {
        if (s < num_segs && s_pred[s_start[s]] != -1) lk++;
    }
    int pos, nsz;
    block_scan(lk, tid, s_wsum, pos, nsz);
    for (int s = t0; s < t0 + CHUNK; ++s) {
        if (s < num_segs) {
            const int st = s_start[s];
            if (s_pred[st] != -1) {
                const int end = (s + 1 < num_segs) ? s_start[s + 1] : TT;
                g_sc[(size_t)b * TT + pos] =
                    (unsigned int)st | ((unsigned int)(end - st) << 14);
                pos++;
            }
        }
    }
    if (tid == 0) g_newsz[b] = nsz;

    // ---- write out_pad row for this batch (coalesced float4) ----
    float* padrow = out_pad + (size_t)b * TT;
    for (int i = tid; i < TT / 4; i += NT) {
        const int p = i * 4;
        vfloat4 v = { p     >= nsz ? 1.f : 0.f,
                      p + 1 >= nsz ? 1.f : 0.f,
                      p + 2 >= nsz ? 1.f : 0.f,
                      p + 3 >= nsz ? 1.f : 0.f };
        *reinterpret_cast<vfloat4*>(padrow + p) = v;
    }
}

// ---------------- K3: segment means -> compacted rows; zero tail ----------------
// 16 lanes per output row (float4 = 16B/lane dense), 4 rows per wave per iter.
// REVERSED group order: k_argmax sweeps logits ascending; gathering descending
// minimizes L3 reuse distance (most-recently-streamed rows consumed first).
__global__ __launch_bounds__(256) void k_out(const float* __restrict__ logits,
                                             const unsigned int* __restrict__ g_sc,
                                             const int* __restrict__ g_newsz,
                                             float* __restrict__ out_logits) {
    __shared__ int s_nsz[BB];
    if (threadIdx.x < BB) s_nsz[threadIdx.x] = g_newsz[threadIdx.x];
    __syncthreads();

    const int lane = threadIdx.x & 63;
    const int wave = threadIdx.x >> 6;
    const int sub  = lane & 15;   // column quad within row
    const int ridx = lane >> 4;   // row within group of 4
    const int gw = blockIdx.x * 4 + wave;      // 2048 blocks * 4 waves = 8192
    const int nw = 2048 * 4;
    const int NG = (BB * TT) >> 2;             // 131072 groups = nw * 16

    #pragma unroll 2
    for (int it = 0; it < 16; it += 2) {
        const int ga = (NG - 1) - (gw + it * nw);        // reversed sweep
        const int gb = (NG - 1) - (gw + (it + 1) * nw);
        const int row0 = ga * 4 + ridx;
        const int row1 = gb * 4 + ridx;
        const int b0 = row0 >> 13, p0 = row0 & (TT - 1);
        const int b1 = row1 >> 13, p1 = row1 & (TT - 1);
        const int nsz0 = s_nsz[b0];
        const int nsz1 = s_nsz[b1];
        const bool v0 = (p0 < nsz0);
        const bool v1 = (p1 < nsz1);
        // issue both metadata loads (independent)
        const unsigned int sc0 = v0 ? g_sc[row0] : 0u;
        const unsigned int sc1 = v1 ? g_sc[row1] : 0u;
        const int st0 = (int)(sc0 & 16383u), cnt0 = (int)(sc0 >> 14);
        const int st1 = (int)(sc1 & 16383u), cnt1 = (int)(sc1 >> 14);
        const float* src0 = logits + ((size_t)b0 * TT + st0) * CC + sub * 4;
        const float* src1 = logits + ((size_t)b1 * TT + st1) * CC + sub * 4;
        // issue both first-frame loads (independent)
        vfloat4 acc0 = {0.f, 0.f, 0.f, 0.f};
        vfloat4 acc1 = {0.f, 0.f, 0.f, 0.f};
        if (v0) acc0 = *reinterpret_cast<const vfloat4*>(src0);
        if (v1) acc1 = *reinterpret_cast<const vfloat4*>(src1);
        // rare tails (mean run length ~1.02)
        if (v0 && cnt0 > 1) {
            for (int f = 1; f < cnt0; ++f)
                acc0 += *reinterpret_cast<const vfloat4*>(src0 + (size_t)f * CC);
            acc0 *= (1.0f / (float)cnt0);
        }
        if (v1 && cnt1 > 1) {
            for (int f = 1; f < cnt1; ++f)
                acc1 += *reinterpret_cast<const vfloat4*>(src1 + (size_t)f * CC);
            acc1 *= (1.0f / (float)cnt1);
        }
        *reinterpret_cast<vfloat4*>(out_logits + (size_t)row0 * CC + sub * 4) = acc0;
        *reinterpret_cast<vfloat4*>(out_logits + (size_t)row1 * CC + sub * 4) = acc1;
    }
}

extern "C" void kernel_launch(void* const* d_in, const int* in_sizes, int n_in,
                              void* d_out, int out_size, void* d_ws, size_t ws_size,
                              hipStream_t stream) {
    const float* logits = (const float*)d_in[0];
    const int*   mask   = (const int*)d_in[1];   // jax bool -> int32 (harness rule)

    int*          preds   = (int*)d_ws;                       // B*T
    unsigned int* g_sc    = (unsigned int*)(preds + (size_t)BB * TT);  // B*T
    int*          g_newsz = (int*)(g_sc + (size_t)BB * TT);   // B

    float* out_logits = (float*)d_out;
    float* out_pad    = out_logits + (size_t)BB * TT * CC;

    hipLaunchKernelGGL(k_argmax, dim3(2048), dim3(256), 0, stream,
                       logits, mask, preds);
    hipLaunchKernelGGL(k_rle, dim3(BB), dim3(1024), 0, stream,
                       preds, g_sc, g_newsz, out_pad);
    hipLaunchKernelGGL(k_out, dim3(2048), dim3(256), 0, stream,
                       logits, g_sc, g_newsz, out_logits);
}

// Round 11
// 68.406 us; speedup vs baseline: 1.0262x; 1.0262x over previous
//
#include <hip/hip_runtime.h>

#define BB 64
#define TT 8192
#define CC 64

typedef float vfloat4 __attribute__((ext_vector_type(4)));

// DPP cross-lane helpers (VALU-only, no LDS). CTRL: 0x141 = row_half_mirror
// (lane^7 within each 8-group), 0x4E = quad_perm [2,3,0,1] (lane^2),
// 0xB1 = quad_perm [1,0,3,2] (lane^1). All stay within an 8-lane group.
template<int CTRL>
__device__ __forceinline__ float dppf(float x) {
    return __int_as_float(__builtin_amdgcn_update_dpp(
        0, __float_as_int(x), CTRL, 0xF, 0xF, true));
}
template<int CTRL>
__device__ __forceinline__ int dppi(int x) {
    return __builtin_amdgcn_update_dpp(0, x, CTRL, 0xF, 0xF, true);
}

// 8-lane argmax reduce for one frame held as 2x float4 across 8 lanes.
__device__ __forceinline__ int frame_argmax(const float4& v0, const float4& v1,
                                            int sub) {
    float m = fmaxf(fmaxf(fmaxf(v0.x, v0.y), fmaxf(v0.z, v0.w)),
                    fmaxf(fmaxf(v1.x, v1.y), fmaxf(v1.z, v1.w)));
    m = fmaxf(m, dppf<0x141>(m));   // ^7
    m = fmaxf(m, dppf<0x4E>(m));    // ^2
    m = fmaxf(m, dppf<0xB1>(m));    // ^1
    const int c0 = sub * 8;
    int t = 64;
    if (v1.w == m) t = c0 + 7;
    if (v1.z == m) t = c0 + 6;
    if (v1.y == m) t = c0 + 5;
    if (v1.x == m) t = c0 + 4;
    if (v0.w == m) t = c0 + 3;
    if (v0.z == m) t = c0 + 2;
    if (v0.y == m) t = c0 + 1;
    if (v0.x == m) t = c0 + 0;
    t = min(t, dppi<0x141>(t));
    t = min(t, dppi<0x4E>(t));
    t = min(t, dppi<0xB1>(t));
    return t;
}

// ---------------- K1: masked argmax over C=64 -> preds[B*T] ----------------
// 8 lanes per frame, 8 cols/lane (2x float4). Two groups paired per iteration:
// 4 independent row loads + 2 mask loads in flight before either reduction.
// Grid exact-fit: 65536 groups = 8192 waves x 8 iters.
__global__ __launch_bounds__(256) void k_argmax(const float* __restrict__ logits,
                                                const int* __restrict__ mask,
                                                int* __restrict__ preds) {
    const int lane = threadIdx.x & 63;
    const int wave = threadIdx.x >> 6;
    const int sub  = lane & 7;    // column octet within frame
    const int fidx = lane >> 3;   // frame within group of 8
    const int gw = blockIdx.x * 4 + wave;   // 2048 blocks * 4 waves = 8192
    const int nw = 2048 * 4;

    #pragma unroll
    for (int it = 0; it < 8; it += 2) {
        const int g0 = gw + it * nw;
        const int g1 = g0 + nw;
        const int f0 = g0 * 8 + fidx;
        const int f1 = g1 * 8 + fidx;
        const int mk0 = mask[f0];
        const int mk1 = mask[f1];
        // issue all row loads before any reduction consumes them
        float4 a0 = {0.f,0.f,0.f,0.f}, a1 = {0.f,0.f,0.f,0.f};
        float4 b0 = {0.f,0.f,0.f,0.f}, b1 = {0.f,0.f,0.f,0.f};
        if (!mk0) {
            const float* row = logits + (size_t)f0 * CC + sub * 8;
            a0 = *reinterpret_cast<const float4*>(row);
            a1 = *reinterpret_cast<const float4*>(row + 4);
        }
        if (!mk1) {
            const float* row = logits + (size_t)f1 * CC + sub * 8;
            b0 = *reinterpret_cast<const float4*>(row);
            b1 = *reinterpret_cast<const float4*>(row + 4);
        }
        int li0 = -1, li1 = -1;
        if (!mk0) li0 = frame_argmax(a0, a1, sub);
        if (!mk1) li1 = frame_argmax(b0, b1, sub);
        if (sub == 0) {
            preds[f0] = li0;
            preds[f1] = li1;
        }
    }
}

// ---------------- block-wide exclusive scan (1024 thr = 16 waves) ----------------
// Wave-level shfl_up scan + 16-entry wave-sum combine. ~3 barriers total.
__device__ __forceinline__ void block_scan(int x, int tid, int* s_wsum,
                                           int& excl, int& total) {
    const int lane = tid & 63;
    const int wv   = tid >> 6;
    int v = x;
    #pragma unroll
    for (int d = 1; d < 64; d <<= 1) {
        int t = __shfl_up(v, d);
        if (lane >= d) v += t;
    }
    __syncthreads();                 // s_wsum safe to overwrite
    if (lane == 63) s_wsum[wv] = v;
    __syncthreads();
    int wpre = 0, tot = 0;
    #pragma unroll
    for (int w = 0; w < 16; ++w) {
        const int s = s_wsum[w];
        tot += s;
        if (w < wv) wpre += s;
    }
    excl = wpre + v - x;
    total = tot;
}

// ---------------- K2: per-batch RLE + compaction scans + pad write ----------------
// One block (1024 threads) per batch. Emits packed (start | count<<14).
__global__ __launch_bounds__(1024) void k_rle(const int* __restrict__ preds,
                                              unsigned int* __restrict__ g_sc,
                                              int* __restrict__ g_newsz,
                                              float* __restrict__ out_pad) {
    __shared__ int s_pred[TT];
    __shared__ int s_start[TT];
    __shared__ int s_wsum[16];
    const int b   = blockIdx.x;
    const int tid = threadIdx.x;
    const int NT  = 1024;
    const int CHUNK = TT / NT;     // 8
    const int t0 = tid * CHUNK;

    // load preds row (int4 vectorized)
    {
        const int4* src = reinterpret_cast<const int4*>(preds + (size_t)b * TT);
        int4* dst = reinterpret_cast<int4*>(s_pred);
        for (int i = tid; i < TT / 4; i += NT) dst[i] = src[i];
    }
    __syncthreads();

    // ---- scan 1: boundaries -> segment starts ----
    int local = 0;
    for (int t = t0; t < t0 + CHUNK; ++t) {
        local += (t == 0) || (s_pred[t] != s_pred[t - 1]);
    }
    int run, num_segs;
    block_scan(local, tid, s_wsum, run, num_segs);
    for (int t = t0; t < t0 + CHUNK; ++t) {
        int bnd = (t == 0) || (s_pred[t] != s_pred[t - 1]);
        if (bnd) { run++; s_start[run - 1] = t; }
    }
    __syncthreads();

    // ---- scan 2: keep -> compacted positions; emit packed (start,count) ----
    int lk = 0;
    for (int s = t0; s < t0 + CHUNK; ++s) {
        if (s < num_segs && s_pred[s_start[s]] != -1) lk++;
    }
    int pos, nsz;
    block_scan(lk, tid, s_wsum, pos, nsz);
    for (int s = t0; s < t0 + CHUNK; ++s) {
        if (s < num_segs) {
            const int st = s_start[s];
            if (s_pred[st] != -1) {
                const int end = (s + 1 < num_segs) ? s_start[s + 1] : TT;
                g_sc[(size_t)b * TT + pos] =
                    (unsigned int)st | ((unsigned int)(end - st) << 14);
                pos++;
            }
        }
    }
    if (tid == 0) g_newsz[b] = nsz;

    // ---- write out_pad row for this batch (coalesced float4) ----
    float* padrow = out_pad + (size_t)b * TT;
    for (int i = tid; i < TT / 4; i += NT) {
        const int p = i * 4;
        vfloat4 v = { p     >= nsz ? 1.f : 0.f,
                      p + 1 >= nsz ? 1.f : 0.f,
                      p + 2 >= nsz ? 1.f : 0.f,
                      p + 3 >= nsz ? 1.f : 0.f };
        *reinterpret_cast<vfloat4*>(padrow + p) = v;
    }
}

// ---------------- K3: segment means -> compacted rows; zero tail ----------------
// 16 lanes per output row (float4 = 16B/lane dense), 4 rows per wave per iter.
// Manually paired iterations (R8 best-measured config; forward order, plain
// stores — nt stores and reversed sweep both tested neutral/negative).
__global__ __launch_bounds__(256) void k_out(const float* __restrict__ logits,
                                             const unsigned int* __restrict__ g_sc,
                                             const int* __restrict__ g_newsz,
                                             float* __restrict__ out_logits) {
    __shared__ int s_nsz[BB];
    if (threadIdx.x < BB) s_nsz[threadIdx.x] = g_newsz[threadIdx.x];
    __syncthreads();

    const int lane = threadIdx.x & 63;
    const int wave = threadIdx.x >> 6;
    const int sub  = lane & 15;   // column quad within row
    const int ridx = lane >> 4;   // row within group of 4
    const int gw = blockIdx.x * 4 + wave;      // 2048 blocks * 4 waves = 8192
    const int nw = 2048 * 4;
    // ngroups = BB*TT/4 = 131072 = nw * 16  -> exactly 16 iters/wave

    #pragma unroll 2
    for (int it = 0; it < 16; it += 2) {
        const int g0 = gw + it * nw;
        const int g1 = g0 + nw;
        const int row0 = g0 * 4 + ridx;
        const int row1 = g1 * 4 + ridx;
        const int b0 = row0 >> 13, p0 = row0 & (TT - 1);
        const int b1 = row1 >> 13, p1 = row1 & (TT - 1);
        const int nsz0 = s_nsz[b0];
        const int nsz1 = s_nsz[b1];
        const bool v0 = (p0 < nsz0);
        const bool v1 = (p1 < nsz1);
        // issue both metadata loads (independent)
        const unsigned int sc0 = v0 ? g_sc[row0] : 0u;
        const unsigned int sc1 = v1 ? g_sc[row1] : 0u;
        const int st0 = (int)(sc0 & 16383u), cnt0 = (int)(sc0 >> 14);
        const int st1 = (int)(sc1 & 16383u), cnt1 = (int)(sc1 >> 14);
        const float* src0 = logits + ((size_t)b0 * TT + st0) * CC + sub * 4;
        const float* src1 = logits + ((size_t)b1 * TT + st1) * CC + sub * 4;
        // issue both first-frame loads (independent)
        vfloat4 acc0 = {0.f, 0.f, 0.f, 0.f};
        vfloat4 acc1 = {0.f, 0.f, 0.f, 0.f};
        if (v0) acc0 = *reinterpret_cast<const vfloat4*>(src0);
        if (v1) acc1 = *reinterpret_cast<const vfloat4*>(src1);
        // rare tails (mean run length ~1.02)
        if (v0 && cnt0 > 1) {
            for (int f = 1; f < cnt0; ++f)
                acc0 += *reinterpret_cast<const vfloat4*>(src0 + (size_t)f * CC);
            acc0 *= (1.0f / (float)cnt0);
        }
        if (v1 && cnt1 > 1) {
            for (int f = 1; f < cnt1; ++f)
                acc1 += *reinterpret_cast<const vfloat4*>(src1 + (size_t)f * CC);
            acc1 *= (1.0f / (float)cnt1);
        }
        *reinterpret_cast<vfloat4*>(out_logits + (size_t)row0 * CC + sub * 4) = acc0;
        *reinterpret_cast<vfloat4*>(out_logits + (size_t)row1 * CC + sub * 4) = acc1;
    }
}

extern "C" void kernel_launch(void* const* d_in, const int* in_sizes, int n_in,
                              void* d_out, int out_size, void* d_ws, size_t ws_size,
                              hipStream_t stream) {
    const float* logits = (const float*)d_in[0];
    const int*   mask   = (const int*)d_in[1];   // jax bool -> int32 (harness rule)

    int*          preds   = (int*)d_ws;                       // B*T
    unsigned int* g_sc    = (unsigned int*)(preds + (size_t)BB * TT);  // B*T
    int*          g_newsz = (int*)(g_sc + (size_t)BB * TT);   // B

    float* out_logits = (float*)d_out;
    float* out_pad    = out_logits + (size_t)BB * TT * CC;

    hipLaunchKernelGGL(k_argmax, dim3(2048), dim3(256), 0, stream,
                       logits, mask, preds);
    hipLaunchKernelGGL(k_rle, dim3(BB), dim3(1024), 0, stream,
                       preds, g_sc, g_newsz, out_pad);
    hipLaunchKernelGGL(k_out, dim3(2048), dim3(256), 0, stream,
                       logits, g_sc, g_newsz, out_logits);
}